// Round 18
// baseline (98.414 us; speedup 1.0000x reference)
//
#include <hip/hip_runtime.h>
#include <math.h>

#define VOCAB 32000
#define EMBED 200
#define HID   10
#define GATES 40
#define BSZ   256
#define SEQ   512
#define PF    8      // steps per prefetch block

#define WROW3 44     // wT pitch: multiple of 4 (b128 align), 4*44%32=16 -> <=4-way alias

__device__ __forceinline__ float rcp_fast(float x) { return __builtin_amdgcn_rcpf(x); }
__device__ __forceinline__ float exp2_fast(float x) { return __builtin_amdgcn_exp2f(x); }
__device__ __forceinline__ float readlane_f(float v, int l) {
    return __int_as_float(__builtin_amdgcn_readlane(__float_as_int(v), l));
}
// DPP quad_perm broadcast of quad-lane Q (pure VALU cross-lane, no LDS)
template <int Q>
__device__ __forceinline__ float quad_bcast(float v) {
    return __int_as_float(__builtin_amdgcn_mov_dpp(
        __float_as_int(v), Q * 0x55, 0xF, 0xF, true));
}

#define SC_SIG (-1.442695041f)   // -log2(e): sigmoid lanes
#define SC_TNH (-2.885390082f)   // -2*log2(e): tanh (g) lanes

// ---------------------------------------------------------------------------
// Kernel A v3: proj[v][g] = (embed[v,:] . Wih[g,:] + bias[g]) * amn[g].
// NO embed staging (the stage->barrier->compute structure capped HBM duty at
// ~40%: proj stuck at ~28us across 3 tile shapes). 8 lanes co-own one row:
// lane i reads float4 at k=c*32+i*4 (coalesced), accumulates all 40 gates
// over its k-subset, butterfly-reduces (xor 1,2,4), writes gates 5i..5i+4.
// W-only LDS (35 KB) -> 4 blocks/CU: cross-block stage/compute overlap.
// ---------------------------------------------------------------------------
__global__ __launch_bounds__(256) void proj_kernel(
    const float* __restrict__ embed, const float* __restrict__ Wih,
    const float* __restrict__ bih,   const float* __restrict__ bhh,
    float* __restrict__ proj)
{
    __shared__ float wT[EMBED * WROW3];   // 35.2 KB
    const int tid = threadIdx.x;

    for (int idx = tid; idx < GATES * EMBED; idx += 256) {
        int g = idx / EMBED, k = idx - g * EMBED;
        wT[k * WROW3 + g] = Wih[idx];
    }
    __syncthreads();

    const int r  = blockIdx.x * 32 + (tid >> 3);   // vocab row
    const int li = tid & 7;                        // k-split lane
    const float* er = embed + (size_t)r * EMBED;

    float acc[GATES];
    #pragma unroll
    for (int g = 0; g < GATES; ++g) acc[g] = 0.f;

#define FMA40(K, EV) do {                                                   \
    const float* wr_ = &wT[(K) * WROW3];                                    \
    _Pragma("unroll")                                                       \
    for (int q = 0; q < 10; ++q) {                                          \
        float4 wv = *(const float4*)(wr_ + q * 4);                          \
        acc[4*q+0] = fmaf((EV), wv.x, acc[4*q+0]);                          \
        acc[4*q+1] = fmaf((EV), wv.y, acc[4*q+1]);                          \
        acc[4*q+2] = fmaf((EV), wv.z, acc[4*q+2]);                          \
        acc[4*q+3] = fmaf((EV), wv.w, acc[4*q+3]);                          \
    }                                                                       \
} while (0)

    #pragma unroll
    for (int c = 0; c < 6; ++c) {                  // 6 x 32 floats = 192
        const int k0 = c * 32 + li * 4;
        float4 e = *(const float4*)(er + k0);
        FMA40(k0 + 0, e.x);
        FMA40(k0 + 1, e.y);
        FMA40(k0 + 2, e.z);
        FMA40(k0 + 3, e.w);
    }
    {                                              // tail: 8 floats, 1/lane
        const int k0 = 192 + li;
        float e = er[k0];
        FMA40(k0, e);
    }
#undef FMA40

    // butterfly reduce over the 8 k-split lanes (all lanes end with full sum)
    #pragma unroll
    for (int g = 0; g < GATES; ++g) {
        float v = acc[g];
        v += __shfl_xor(v, 1, 64);
        v += __shfl_xor(v, 2, 64);
        v += __shfl_xor(v, 4, 64);
        acc[g] = v;
    }

    // lane i writes gates 5i..5i+4 (bias + activation exp2-scale fold)
    const int g0 = li * 5;
    #pragma unroll
    for (int j = 0; j < 5; ++j) {
        int g = g0 + j;
        float sc = (g >= 20 && g < 30) ? SC_TNH : SC_SIG;
        proj[(size_t)r * GATES + g] = (acc[g] + bih[g] + bhh[g]) * sc;
    }
}

// ---------------------------------------------------------------------------
// Kernel B: recurrence — byte-identical to the R12/R17-passing 68.8us version.
// ---------------------------------------------------------------------------
__global__ __launch_bounds__(64, 1) void lstm_rec(
    const int*   __restrict__ tok,  const float* __restrict__ proj,
    const float* __restrict__ h0,   const float* __restrict__ c0,
    const float* __restrict__ Whh,
    const float* __restrict__ W1,   const float* __restrict__ b1,
    const float* __restrict__ lng,  const float* __restrict__ lnb,
    const float* __restrict__ W2,   const float* __restrict__ b2,
    float* __restrict__ out)
{
    __shared__ int tok_s[SEQ + 2 * PF];

    const int b    = blockIdx.x;
    const int lane = threadIdx.x;
    const int j0   = min(lane >> 2, HID - 1);  // hidden unit
    const int k4   = lane & 3;                 // gate class i/f/g/o
    const int gate = k4 * HID + j0;            // row in [i|f|g|o]-major order

    #pragma unroll
    for (int k = 0; k < SEQ / 64; ++k)
        tok_s[k * 64 + lane] = tok[b * SEQ + k * 64 + lane];
    if (lane < 2 * PF) tok_s[SEQ + lane] = 0;  // tail pad: safe addresses
    __syncthreads();

    const float am  = (k4 == 2) ? 2.f : 1.f;
    const float amc = 1.f - am;
    const float amn = (k4 == 2) ? SC_TNH : SC_SIG;

    // W_hh row, pre-scaled so dot output feeds exp2 directly
    float w[HID];
    #pragma unroll
    for (int j = 0; j < HID; ++j) w[j] = amn * Whh[gate * HID + j];

    float hs[HID];
    #pragma unroll
    for (int u = 0; u < HID; ++u) hs[u] = h0[b * HID + u];
    float c_own = c0[b * HID + j0];

    // ---- prologue ----
    int   tk_cur[PF], tk_nxt[PF];
    float gx_cur[PF], gx_nxt[PF];
    #pragma unroll
    for (int k = 0; k < PF; ++k) tk_cur[k] = tok_s[k];
    #pragma unroll
    for (int k = 0; k < PF; ++k) gx_cur[k] = proj[tk_cur[k] * GATES + gate];
    #pragma unroll
    for (int k = 0; k < PF; ++k) tk_nxt[k] = tok_s[PF + k];

    for (int s0 = 0; s0 < SEQ; s0 += PF) {
        #pragma unroll
        for (int k = 0; k < PF; ++k)
            gx_nxt[k] = proj[tk_nxt[k] * GATES + gate];
        #pragma unroll
        for (int k = 0; k < PF; ++k)
            tk_cur[k] = tok_s[s0 + 2 * PF + k];

        #pragma unroll
        for (int k = 0; k < PF; ++k) {
            float a0 = gx_cur[k], a1 = 0.f, a2 = 0.f, a3 = 0.f;
            a0 = fmaf(hs[0], w[0], a0); a1 = fmaf(hs[1], w[1], a1);
            a2 = fmaf(hs[2], w[2], a2); a3 = fmaf(hs[3], w[3], a3);
            a0 = fmaf(hs[4], w[4], a0); a1 = fmaf(hs[5], w[5], a1);
            a2 = fmaf(hs[6], w[6], a2); a3 = fmaf(hs[7], w[7], a3);
            a0 = fmaf(hs[8], w[8], a0); a1 = fmaf(hs[9], w[9], a1);
            float dt = (a0 + a2) + (a1 + a3);

            float t   = exp2_fast(dt);
            float sg  = rcp_fast(1.f + t);
            float val = fmaf(am, sg, amc);

            float iv = quad_bcast<0>(val);
            float fv = quad_bcast<1>(val);
            float gv = quad_bcast<2>(val);
            float ov = quad_bcast<3>(val);

            c_own = fmaf(fv, c_own, iv * gv);
            float t2 = exp2_fast(c_own * SC_TNH);
            float th = fmaf(2.f, rcp_fast(1.f + t2), -1.f);
            float h_own = ov * th;

            hs[0] = readlane_f(h_own, 0);  hs[1] = readlane_f(h_own, 4);
            hs[2] = readlane_f(h_own, 8);  hs[3] = readlane_f(h_own, 12);
            hs[4] = readlane_f(h_own, 16); hs[5] = readlane_f(h_own, 20);
            hs[6] = readlane_f(h_own, 24); hs[7] = readlane_f(h_own, 28);
            hs[8] = readlane_f(h_own, 32); hs[9] = readlane_f(h_own, 36);
        }

        #pragma unroll
        for (int k = 0; k < PF; ++k) {
            gx_cur[k] = gx_nxt[k];
            tk_nxt[k] = tk_cur[k];
        }
    }

    // head: z = hn@W1^T + b1 ; LayerNorm(5) ; sigmoid(z@W2^T + b2)
    if (lane == 0) {
        float z[5];
        float mu = 0.f;
        #pragma unroll
        for (int m = 0; m < 5; ++m) {
            float a = b1[m];
            #pragma unroll
            for (int j = 0; j < HID; ++j) a = fmaf(hs[j], W1[m * HID + j], a);
            z[m] = a; mu += a;
        }
        mu *= 0.2f;
        float var = 0.f;
        #pragma unroll
        for (int m = 0; m < 5; ++m) { float d = z[m] - mu; var = fmaf(d, d, var); }
        var *= 0.2f;
        float rs = rsqrtf(var + 1e-5f);
        float acc = b2[0];
        #pragma unroll
        for (int m = 0; m < 5; ++m) {
            float zn = fmaf((z[m] - mu) * rs, lng[m], lnb[m]);
            acc = fmaf(zn, W2[m], acc);
        }
        out[b] = 1.f / (1.f + __expf(-acc));
    }
}

extern "C" void kernel_launch(void* const* d_in, const int* in_sizes, int n_in,
                              void* d_out, int out_size, void* d_ws, size_t ws_size,
                              hipStream_t stream) {
    const int*   tok   = (const int*)  d_in[0];
    const float* h0    = (const float*)d_in[1];
    const float* c0    = (const float*)d_in[2];
    const float* embed = (const float*)d_in[3];
    const float* Wih   = (const float*)d_in[4];
    const float* Whh   = (const float*)d_in[5];
    const float* bih   = (const float*)d_in[6];
    const float* bhh   = (const float*)d_in[7];
    const float* W1    = (const float*)d_in[8];
    const float* b1    = (const float*)d_in[9];
    const float* lng   = (const float*)d_in[10];
    const float* lnb   = (const float*)d_in[11];
    const float* W2    = (const float*)d_in[12];
    const float* b2    = (const float*)d_in[13];
    float* out  = (float*)d_out;
    float* proj = (float*)d_ws;   // VOCAB*GATES*4 = 5.12 MB

    hipLaunchKernelGGL(proj_kernel, dim3(VOCAB / 32), dim3(256), 0, stream,
                       embed, Wih, bih, bhh, proj);
    hipLaunchKernelGGL(lstm_rec, dim3(BSZ), dim3(64), 0, stream,
                       tok, proj, h0, c0, Whh, W1, b1, lng, lnb, W2, b2, out);
}